// Round 1
// baseline (1243.975 us; speedup 1.0000x reference)
//
#include <hip/hip_runtime.h>

#define N_ 16
#define C_ 128
#define H_ 56
#define W_ 56
#define HW_ 3136

// ---------------------------------------------------------------------------
// K1: t2[n,co,h,w] = sum_{ci,j} x[n,ci,h,w+j-1] * w2[co,ci,j]   (zero-pad w)
// Grid: (H_, N_), 256 threads. LDS-stage one x row (all 128 ch, padded).
// ---------------------------------------------------------------------------
__global__ __launch_bounds__(256) void k1_conv1x3(const float* __restrict__ x,
                                                  const float* __restrict__ w2,
                                                  float* __restrict__ t2) {
    int h = blockIdx.x, n = blockIdx.y;
    __shared__ float xs[C_ * 58];
    int tid = threadIdx.x;
    const float* xrow = x + (long)(n * C_) * HW_ + h * W_;
    for (int i = tid; i < C_ * W_; i += 256) {
        int ci = i / W_, w = i % W_;
        xs[ci * 58 + w + 1] = xrow[ci * HW_ + w];
    }
    if (tid < C_) { xs[tid * 58] = 0.f; xs[tid * 58 + 57] = 0.f; }
    __syncthreads();

    int co = tid >> 1;
    int wb = (tid & 1) * 28;
    float acc[28];
#pragma unroll
    for (int w = 0; w < 28; w++) acc[w] = 0.f;

    const float* wp = w2 + co * C_ * 3;
    for (int ci = 0; ci < C_; ci++) {
        float w0 = wp[ci * 3 + 0];
        float w1 = wp[ci * 3 + 1];
        float w2v = wp[ci * 3 + 2];
        int base = ci * 58 + wb;
        float xv[30];
#pragma unroll
        for (int t = 0; t < 30; t++) xv[t] = xs[base + t];
#pragma unroll
        for (int w = 0; w < 28; w++)
            acc[w] += xv[w] * w0 + xv[w + 1] * w1 + xv[w + 2] * w2v;
    }

    float* orow = t2 + (long)(n * C_ + co) * HW_ + h * W_ + wb;
#pragma unroll
    for (int w = 0; w < 28; w++) orow[w] = acc[w];
}

// ---------------------------------------------------------------------------
// K2: t3[n,k,a,b] = (1/56) * sum_{h,w} x[n,a,h,w+2k-6] * x[n,b,h,w]
// Split-K over 4 chunks of 784 hw-positions; atomicAdd into zeroed t3.
// Grid: (4, 7, N_), 256 threads, 8x8 register tile per thread.
// ---------------------------------------------------------------------------
__global__ __launch_bounds__(256) void k2_corr(const float* __restrict__ x,
                                               float* __restrict__ t3) {
    int hc = blockIdx.x, k = blockIdx.y, n = blockIdx.z;
    int shift = 2 * k - 6;
    __shared__ float As[16 * 129];
    __shared__ float Bs[16 * 129];
    int tid = threadIdx.x;
    int ta = tid >> 4, tb = tid & 15;
    float acc[8][8];
#pragma unroll
    for (int i = 0; i < 8; i++)
#pragma unroll
        for (int j = 0; j < 8; j++) acc[i][j] = 0.f;

    const float* xn = x + (long)n * C_ * HW_;
    for (int kt = 0; kt < 49; kt++) {
        int hwbase = hc * 784 + kt * 16;
        for (int i = tid; i < 2048; i += 256) {
            int kk = i & 15, c = i >> 4;
            int hw = hwbase + kk;
            int h = hw / 56, w = hw % 56;
            int wp = w + shift;
            float av = (wp >= 0 && wp < 56) ? xn[c * HW_ + h * 56 + wp] : 0.f;
            float bv = xn[c * HW_ + h * 56 + w];
            As[kk * 129 + c] = av;
            Bs[kk * 129 + c] = bv;
        }
        __syncthreads();
#pragma unroll 4
        for (int kk = 0; kk < 16; kk++) {
            float aF[8], bF[8];
#pragma unroll
            for (int i = 0; i < 8; i++) aF[i] = As[kk * 129 + ta + i * 16];
#pragma unroll
            for (int j = 0; j < 8; j++) bF[j] = Bs[kk * 129 + tb + j * 16];
#pragma unroll
            for (int i = 0; i < 8; i++)
#pragma unroll
                for (int j = 0; j < 8; j++) acc[i][j] += aF[i] * bF[j];
        }
        __syncthreads();
    }

    float* t3p = t3 + (long)(n * 7 + k) * C_ * C_;
    const float inv56 = 1.0f / 56.0f;
#pragma unroll
    for (int i = 0; i < 8; i++) {
        int a = ta + i * 16;
#pragma unroll
        for (int j = 0; j < 8; j++) {
            int b = tb + j * 16;
            atomicAdd(&t3p[a * C_ + b], acc[i][j] * inv56);
        }
    }
}

// ---------------------------------------------------------------------------
// K3: t10[n,b,h,w] = sum_{a,k} s[n,k,a,b] * t2[n,a,h+k-3,w]
//     s[n,k,a,b] = t3[n,k,a,b] * p6w[a,k] * p9w[k,b] / sqrt(896)
// Epilogue fuses t7 (dw 1x5 on t2), t8 (dw 5x5 dil2 on x): out = t8 - t10 + t7
// Grid: (28, N_) -> each block: all 128 b x 112 hw (2 rows). 256 threads.
// ---------------------------------------------------------------------------
__global__ __launch_bounds__(256) void k3_final(const float* __restrict__ x,
                                                const float* __restrict__ t2,
                                                const float* __restrict__ t3,
                                                const float* __restrict__ p6w,
                                                const float* __restrict__ w7,
                                                const float* __restrict__ w8,
                                                const float* __restrict__ p9w,
                                                float* __restrict__ out) {
    int tile = blockIdx.x;  // 0..27
    int n = blockIdx.y;
    int h0 = tile * 2;
    __shared__ float sA[16 * 129];  // [kk][b]
    __shared__ float bB[16 * 113];  // [kk][hw]
    int tid = threadIdx.x;
    int tb = tid >> 4, tw = tid & 15;
    const float rs = 0.033407655f;  // 1/sqrt(896)

    float acc[8][7];
#pragma unroll
    for (int i = 0; i < 8; i++)
#pragma unroll
        for (int j = 0; j < 7; j++) acc[i][j] = 0.f;

    for (int kt = 0; kt < 56; kt++) {
        int akbase = kt * 16;
        // stage A: scaled t3 slice chunk, [kk][b]
        for (int i = tid; i < 2048; i += 256) {
            int b = i & 127, kk = i >> 7;
            int ak = akbase + kk;
            int a = ak / 7, k = ak - a * 7;
            float v = t3[((long)(n * 7 + k) * C_ + a) * C_ + b] *
                      p6w[a * 7 + k] * p9w[k * C_ + b] * rs;
            sA[kk * 129 + b] = v;
        }
        // stage B: shifted t2 rows, [kk][hw]
        for (int i = tid; i < 1792; i += 256) {
            int kk = i / 112, hw = i % 112;
            int ak = akbase + kk;
            int a = ak / 7, k = ak - a * 7;
            int hh = h0 + hw / 56 + k - 3;
            int w = hw % 56;
            float v = (hh >= 0 && hh < 56)
                          ? t2[(long)(n * C_ + a) * HW_ + hh * 56 + w]
                          : 0.f;
            bB[kk * 113 + hw] = v;
        }
        __syncthreads();
#pragma unroll 4
        for (int kk = 0; kk < 16; kk++) {
            float aF[8], bF[7];
#pragma unroll
            for (int i = 0; i < 8; i++) aF[i] = sA[kk * 129 + tb + i * 16];
#pragma unroll
            for (int j = 0; j < 7; j++) bF[j] = bB[kk * 113 + tw * 7 + j];
#pragma unroll
            for (int i = 0; i < 8; i++)
#pragma unroll
                for (int j = 0; j < 7; j++) acc[i][j] += aF[i] * bF[j];
        }
        __syncthreads();
    }

    // epilogue: out = t8 - t10 + t7
#pragma unroll 1
    for (int i = 0; i < 8; i++) {
        int b = tb + i * 16;
        float w7r[5];
#pragma unroll
        for (int q = 0; q < 5; q++) w7r[q] = w7[b * 5 + q];
        float w8r[25];
#pragma unroll
        for (int q = 0; q < 25; q++) w8r[q] = w8[b * 25 + q];
        const float* xb = x + (long)(n * C_ + b) * HW_;
        const float* t2b = t2 + (long)(n * C_ + b) * HW_;
        float* ob = out + (long)(n * C_ + b) * HW_;
#pragma unroll 1
        for (int j = 0; j < 7; j++) {
            int hw = tw * 7 + j;
            int h = h0 + hw / 56;
            int w = hw % 56;
            float t7v = 0.f;
#pragma unroll
            for (int q = 0; q < 5; q++) {
                int wq = w + q - 2;
                if (wq >= 0 && wq < 56) t7v += t2b[h * 56 + wq] * w7r[q];
            }
            float t8v = 0.f;
#pragma unroll
            for (int p = 0; p < 5; p++) {
                int hp = h + 2 * p - 4;
                if (hp < 0 || hp >= 56) continue;
#pragma unroll
                for (int q = 0; q < 5; q++) {
                    int wq = w + 2 * q - 4;
                    if (wq >= 0 && wq < 56)
                        t8v += xb[hp * 56 + wq] * w8r[p * 5 + q];
                }
            }
            ob[h * 56 + w] = t8v - acc[i][j] + t7v;
        }
    }
}

extern "C" void kernel_launch(void* const* d_in, const int* in_sizes, int n_in,
                              void* d_out, int out_size, void* d_ws, size_t ws_size,
                              hipStream_t stream) {
    const float* x = (const float*)d_in[0];
    const float* w2 = (const float*)d_in[1];
    const float* p6w = (const float*)d_in[2];
    const float* w7 = (const float*)d_in[3];
    const float* w8 = (const float*)d_in[4];
    const float* p9w = (const float*)d_in[5];
    float* outp = (float*)d_out;

    float* t2ws = (float*)d_ws;                    // 16*128*3136 floats
    float* t3ws = t2ws + (size_t)N_ * C_ * HW_;    // 16*7*128*128 floats

    hipMemsetAsync(t3ws, 0, (size_t)N_ * 7 * C_ * C_ * sizeof(float), stream);
    k1_conv1x3<<<dim3(H_, N_), 256, 0, stream>>>(x, w2, t2ws);
    k2_corr<<<dim3(4, 7, N_), 256, 0, stream>>>(x, t3ws);
    k3_final<<<dim3(28, N_), 256, 0, stream>>>(x, t2ws, t3ws, p6w, w7, w8, p9w, outp);
}

// Round 2
// 763.172 us; speedup vs baseline: 1.6300x; 1.6300x over previous
//
#include <hip/hip_runtime.h>

#define N_ 16
#define C_ 128
#define H_ 56
#define W_ 56
#define HW_ 3136

typedef __bf16 bf16x8 __attribute__((ext_vector_type(8)));
typedef __bf16 bf16x2 __attribute__((ext_vector_type(2)));
typedef float f32x4 __attribute__((ext_vector_type(4)));

#define XT_PLANE 3808   // 68*56 per channel
#define XT_PER_N 487424 // 128*3808
#define T2_PLANE 3472   // 62*56 per channel
#define T2_PER_N 444416 // 128*3472
#define S_PER_N 114688  // 128*896

// ---------------------------------------------------------------------------
// P1: xT[n][c][wp][h] = x[n][c][h][wp-6] for wp in [6,62), else 0.  bf16.
// ---------------------------------------------------------------------------
__global__ __launch_bounds__(256) void p1_transpose(const float* __restrict__ x,
                                                    __bf16* __restrict__ xT) {
    int c = blockIdx.x, n = blockIdx.y;
    __shared__ float xs[56 * 57];
    int tid = threadIdx.x;
    const float* xp = x + (size_t)(n * C_ + c) * HW_;
    for (int i = tid; i < HW_; i += 256) {
        int h = i / 56, w = i - 56 * h;
        xs[w * 57 + h] = xp[i];
    }
    __syncthreads();
    __bf16* op = xT + (size_t)(n * C_ + c) * XT_PLANE;
    for (int j = tid; j < XT_PLANE; j += 256) {
        int wp = j / 56, h = j - 56 * wp;
        float v = (wp >= 6 && wp < 62) ? xs[(wp - 6) * 57 + h] : 0.f;
        op[j] = (__bf16)v;
    }
}

// ---------------------------------------------------------------------------
// K1: t2 = dense 1x3 conv (fp32 compute), store bf16 into h-padded t2pb.
// t2pb[n][co][h+3][w]. Pad rows come from memset.
// ---------------------------------------------------------------------------
__global__ __launch_bounds__(256) void k1_conv1x3(const float* __restrict__ x,
                                                  const float* __restrict__ w2,
                                                  __bf16* __restrict__ t2pb) {
    int h = blockIdx.x, n = blockIdx.y;
    __shared__ float xs[C_ * 58];
    int tid = threadIdx.x;
    const float* xrow = x + (size_t)(n * C_) * HW_ + h * W_;
    for (int i = tid; i < C_ * W_; i += 256) {
        int ci = i / W_, w = i % W_;
        xs[ci * 58 + w + 1] = xrow[ci * HW_ + w];
    }
    if (tid < C_) { xs[tid * 58] = 0.f; xs[tid * 58 + 57] = 0.f; }
    __syncthreads();

    int co = tid >> 1;
    int wb = (tid & 1) * 28;
    float acc[28];
#pragma unroll
    for (int w = 0; w < 28; w++) acc[w] = 0.f;

    const float* wp = w2 + co * C_ * 3;
    for (int ci = 0; ci < C_; ci++) {
        float w0 = wp[ci * 3 + 0];
        float w1 = wp[ci * 3 + 1];
        float w2v = wp[ci * 3 + 2];
        int base = ci * 58 + wb;
        float xv[30];
#pragma unroll
        for (int t = 0; t < 30; t++) xv[t] = xs[base + t];
#pragma unroll
        for (int w = 0; w < 28; w++)
            acc[w] += xv[w] * w0 + xv[w + 1] * w1 + xv[w + 2] * w2v;
    }

    __bf16* orow = t2pb + ((size_t)(n * C_ + co) * 62 + (h + 3)) * 56 + wb;
#pragma unroll
    for (int w = 0; w < 28; w += 2) {
        bf16x2 pr = {(__bf16)acc[w], (__bf16)acc[w + 1]};
        *(bf16x2*)&orow[w] = pr;
    }
}

// ---------------------------------------------------------------------------
// K2: t3[n,k,a,b] += (1/56) sum_{w-col, h} xT[a][w+2k][h] * xT[b][w+6][h]
// MFMA 16x16x32 bf16. Grid (4,7,16): 4-way split over the 56 w-columns.
// Block = 128x128 output, 4 waves in 2x2, 64x64 per wave. K per col = 64
// (h 0..55 + 8 zero pad). atomicAdd fp32 into zeroed t3.
// ---------------------------------------------------------------------------
__global__ __launch_bounds__(256) void k2_mfma(const __bf16* __restrict__ xT,
                                               float* __restrict__ t3) {
    int hc = blockIdx.x, k = blockIdx.y, n = blockIdx.z;
    __shared__ __align__(16) __bf16 As[128 * 72];
    __shared__ __align__(16) __bf16 Bs[128 * 72];
    int tid = threadIdx.x;
    int wv = tid >> 6, lane = tid & 63;
    int lm = lane & 15, lq = lane >> 4;
    int wi = wv >> 1, wj = wv & 1;

    f32x4 acc[4][4];
    f32x4 zero4 = {0.f, 0.f, 0.f, 0.f};
#pragma unroll
    for (int i = 0; i < 4; i++)
#pragma unroll
        for (int j = 0; j < 4; j++) acc[i][j] = zero4;

    const __bf16* xTn = xT + (size_t)n * XT_PER_N;
    __bf16 bz = (__bf16)0.f;
    bf16x8 vzero = {bz, bz, bz, bz, bz, bz, bz, bz};

    for (int ci = 0; ci < 14; ci++) {
        int w = hc * 14 + ci;
        // stage: A[a][kk]=xT[a][w+2k][kk], B[b][kk]=xT[b][w+6][kk]; kk=h, 56..63 zero
#pragma unroll
        for (int u = 0; u < 4; u++) {
            int v = tid + u * 256;       // [0,1024)
            int m = v & 7, a = v >> 3;   // octet m, row a
            bf16x8 va = vzero, vb = vzero;
            if (m < 7) {
                va = *(const bf16x8*)(xTn + (a * 68 + (w + 2 * k)) * 56 + 8 * m);
                vb = *(const bf16x8*)(xTn + (a * 68 + (w + 6)) * 56 + 8 * m);
            }
            *(bf16x8*)&As[a * 72 + 8 * m] = va;
            *(bf16x8*)&Bs[a * 72 + 8 * m] = vb;
        }
        __syncthreads();
#pragma unroll
        for (int kb = 0; kb < 2; kb++) {
            bf16x8 av[4], bv[4];
#pragma unroll
            for (int i = 0; i < 4; i++)
                av[i] = *(const bf16x8*)&As[(wi * 64 + i * 16 + lm) * 72 + kb * 32 + lq * 8];
#pragma unroll
            for (int j = 0; j < 4; j++)
                bv[j] = *(const bf16x8*)&Bs[(wj * 64 + j * 16 + lm) * 72 + kb * 32 + lq * 8];
#pragma unroll
            for (int i = 0; i < 4; i++)
#pragma unroll
                for (int j = 0; j < 4; j++)
                    acc[i][j] = __builtin_amdgcn_mfma_f32_16x16x32_bf16(av[i], bv[j], acc[i][j], 0, 0, 0);
        }
        __syncthreads();
    }

    float* t3p = t3 + (size_t)(n * 7 + k) * (C_ * C_);
    const float inv56 = 1.0f / 56.0f;
#pragma unroll
    for (int i = 0; i < 4; i++)
#pragma unroll
        for (int j = 0; j < 4; j++)
#pragma unroll
            for (int r = 0; r < 4; r++) {
                int a = wi * 64 + i * 16 + lq * 4 + r;
                int b = wj * 64 + j * 16 + lm;
                atomicAdd(&t3p[a * C_ + b], acc[i][j][r] * inv56);
            }
}

// ---------------------------------------------------------------------------
// s-prep: s[n][b][ak] = bf16( t3[n][k][a][b] * p6w[a][k] * p9w[k][b] / sqrt(896) )
// ---------------------------------------------------------------------------
__global__ __launch_bounds__(256) void sprep(const float* __restrict__ t3,
                                             const float* __restrict__ p6w,
                                             const float* __restrict__ p9w,
                                             __bf16* __restrict__ s) {
    int idx = blockIdx.x * 256 + threadIdx.x;  // < 16*128*896
    int n = idx / S_PER_N;
    int rem = idx - n * S_PER_N;
    int b = rem / 896;
    int ak = rem - b * 896;
    int a = ak / 7, k = ak - 7 * a;
    const float rs = 0.03340766f;  // 1/sqrt(896)
    float v = t3[((size_t)(n * 7 + k) * C_ + a) * C_ + b] * p6w[a * 7 + k] *
              p9w[k * C_ + b] * rs;
    s[idx] = (__bf16)v;
}

// ---------------------------------------------------------------------------
// K3: t10[b][hw] = sum_ak s[b][ak] * t2pb_lin[a*3472 + hw + 56k]   (per n)
// MFMA, block tile 128(b) x 128(hw), K=896 in 14 chunks of 64.
// Bs uses XOR-swizzled [hw][ak] layout. Epilogue fuses t7/t8 fp32.
// ---------------------------------------------------------------------------
__global__ __launch_bounds__(256) void k3_mfma(const float* __restrict__ x,
                                               const __bf16* __restrict__ s,
                                               const __bf16* __restrict__ t2pb,
                                               const float* __restrict__ w7,
                                               const float* __restrict__ w8,
                                               float* __restrict__ out) {
    int tile = blockIdx.x;  // 0..24 (tile 24 partial: 64 valid hw)
    int n = blockIdx.y;
    int hw0 = tile * 128;
    __shared__ __align__(16) __bf16 As[128 * 72];
    __shared__ __align__(16) __bf16 Bs[128 * 72];
    int tid = threadIdx.x;
    int wv = tid >> 6, lane = tid & 63;
    int lm = lane & 15, lq = lane >> 4;
    int wi = wv >> 1, wj = wv & 1;

    f32x4 acc[4][4];
    f32x4 zero4 = {0.f, 0.f, 0.f, 0.f};
#pragma unroll
    for (int i = 0; i < 4; i++)
#pragma unroll
        for (int j = 0; j < 4; j++) acc[i][j] = zero4;

    const __bf16* s_n = s + (size_t)n * S_PER_N;
    const __bf16* t2n = t2pb + (size_t)n * T2_PER_N;

    for (int kb = 0; kb < 14; kb++) {
        // stage A: As[b][akl] = s_n[b*896 + kb*64 + akl], 16B vectors
#pragma unroll
        for (int u = 0; u < 4; u++) {
            int v = tid + u * 256;
            int m = v & 7, b = v >> 3;
            *(bf16x8*)&As[b * 72 + 8 * m] =
                *(const bf16x8*)(s_n + b * 896 + kb * 64 + 8 * m);
        }
        // stage B: Bs[row=hw_local][ak swizzled]; src linear in hw
#pragma unroll
        for (int pass = 0; pass < 2; pass++) {
            int u = tid + pass * 256;
            int o = u & 15;       // hw octet
            int p = u >> 4;       // ak pair, [0,32)
            int ak0 = kb * 64 + 2 * p;
            int a0 = ak0 / 7, k0 = ak0 - 7 * a0;
            int ak1 = ak0 + 1;
            int a1 = ak1 / 7, k1 = ak1 - 7 * a1;
            int hwg = hw0 + 8 * o;
            bf16x8 v0 = *(const bf16x8*)(t2n + a0 * T2_PLANE + hwg + 56 * k0);
            bf16x8 v1 = *(const bf16x8*)(t2n + a1 * T2_PLANE + hwg + 56 * k1);
            int gs = p >> 2;          // ak group (of 8)
            int off = (2 * p) & 7;    // offset within group (even)
#pragma unroll
            for (int j = 0; j < 8; j++) {
                int row = 8 * o + j;
                int phys = ((gs ^ (o & 7)) << 3) + off;  // row>>3 == o
                bf16x2 pr = {v0[j], v1[j]};
                *(bf16x2*)&Bs[row * 72 + phys] = pr;
            }
        }
        __syncthreads();
#pragma unroll
        for (int kbi = 0; kbi < 2; kbi++) {
            bf16x8 av[4], bv[4];
#pragma unroll
            for (int i = 0; i < 4; i++)
                av[i] = *(const bf16x8*)&As[(wi * 64 + i * 16 + lm) * 72 + kbi * 32 + lq * 8];
#pragma unroll
            for (int j = 0; j < 4; j++) {
                int row = wj * 64 + j * 16 + lm;
                int g = kbi * 4 + lq;
                int phys_g = g ^ ((row >> 3) & 7);
                bv[j] = *(const bf16x8*)&Bs[row * 72 + phys_g * 8];
            }
#pragma unroll
            for (int i = 0; i < 4; i++)
#pragma unroll
                for (int j = 0; j < 4; j++)
                    acc[i][j] = __builtin_amdgcn_mfma_f32_16x16x32_bf16(av[i], bv[j], acc[i][j], 0, 0, 0);
        }
        __syncthreads();
    }

    // epilogue: out = t8 - t10 + t7
    const float* xn = x + (size_t)n * C_ * HW_;
#pragma unroll 1
    for (int j = 0; j < 4; j++) {
        int hw = hw0 + wj * 64 + j * 16 + lm;
        if (hw >= HW_) continue;
        int h = hw / 56, w = hw - 56 * h;
#pragma unroll 1
        for (int i = 0; i < 4; i++) {
#pragma unroll
            for (int r = 0; r < 4; r++) {
                int b = wi * 64 + i * 16 + lq * 4 + r;
                float t10v = acc[i][j][r];
                const __bf16* t2b = t2n + b * T2_PLANE + (h + 3) * 56;
                float t7v = 0.f;
#pragma unroll
                for (int q = 0; q < 5; q++) {
                    int wq = w + q - 2;
                    if (wq >= 0 && wq < 56) t7v += (float)t2b[wq] * w7[b * 5 + q];
                }
                const float* xb = xn + b * HW_;
                float t8v = 0.f;
#pragma unroll
                for (int p = 0; p < 5; p++) {
                    int hp = h + 2 * p - 4;
                    if (hp < 0 || hp >= 56) continue;
#pragma unroll
                    for (int q = 0; q < 5; q++) {
                        int wq = w + 2 * q - 4;
                        if (wq >= 0 && wq < 56)
                            t8v += xb[hp * 56 + wq] * w8[b * 25 + p * 5 + q];
                    }
                }
                out[(size_t)(n * C_ + b) * HW_ + hw] = t8v - t10v + t7v;
            }
        }
    }
}

extern "C" void kernel_launch(void* const* d_in, const int* in_sizes, int n_in,
                              void* d_out, int out_size, void* d_ws, size_t ws_size,
                              hipStream_t stream) {
    const float* x = (const float*)d_in[0];
    const float* w2 = (const float*)d_in[1];
    const float* p6w = (const float*)d_in[2];
    const float* w7 = (const float*)d_in[3];
    const float* w8 = (const float*)d_in[4];
    const float* p9w = (const float*)d_in[5];
    float* outp = (float*)d_out;

    // workspace layout (bytes):
    //   [0, 15597568)            xT bf16  (overlaid by s bf16 after k2)
    //   [15597568, 29818880)     t2pb bf16 (h-padded)
    //   [29818880, 37158912)     t3 fp32
    __bf16* xT = (__bf16*)d_ws;
    __bf16* t2pb = xT + (size_t)N_ * C_ * XT_PLANE;        // 7,798,784 elems
    float* t3 = (float*)(t2pb + (size_t)N_ * C_ * T2_PLANE);  // after 7,110,656 elems
    __bf16* s = xT;  // overlay: xT dead after k2

    hipMemsetAsync(t2pb, 0, (size_t)N_ * C_ * T2_PLANE * sizeof(__bf16), stream);
    hipMemsetAsync(t3, 0, (size_t)N_ * 7 * C_ * C_ * sizeof(float), stream);

    p1_transpose<<<dim3(C_, N_), 256, 0, stream>>>(x, xT);
    k1_conv1x3<<<dim3(H_, N_), 256, 0, stream>>>(x, w2, t2pb);
    k2_mfma<<<dim3(4, 7, N_), 256, 0, stream>>>(xT, t3);
    sprep<<<dim3((N_ * S_PER_N) / 256), 256, 0, stream>>>(t3, p6w, p9w, s);
    k3_mfma<<<dim3(25, N_), 256, 0, stream>>>(x, s, t2pb, w7, w8, outp);
}

// Round 3
// 313.314 us; speedup vs baseline: 3.9704x; 2.4358x over previous
//
#include <hip/hip_runtime.h>

#define N_ 16
#define C_ 128
#define H_ 56
#define W_ 56
#define HW_ 3136

typedef __bf16 bf16x8 __attribute__((ext_vector_type(8)));
typedef __bf16 bf16x2 __attribute__((ext_vector_type(2)));
typedef float f32x4 __attribute__((ext_vector_type(4)));

#define XT_PER_N 401408   // 128*3136 (unpadded transposed x, bf16)
#define T2_PLANE 3472     // 62*56 per channel (h-padded t2, bf16)
#define T2_PER_N 444416   // 128*3472
#define S_PER_N 114688    // 128*896
#define T10_PER_N 401408  // 128*3136

// workspace byte offsets
#define WS_T10_OFF   3670016u   // overlays xT tail + t3 head (both dead by k3)
#define WS_T3_OFF    12845056u
#define WS_T2PB_OFF  20185088u
#define WS_W2T_OFF   34406400u  // end 34603008 < 37.2MB proven budget

// ---------------------------------------------------------------------------
// w2T[ci*3+j][co] = w2[co][ci*3+j]  (fp32, for coalesced float2 reads in k1)
// ---------------------------------------------------------------------------
__global__ __launch_bounds__(256) void w2t_prep(const float* __restrict__ w2,
                                                float* __restrict__ w2T) {
    int idx = blockIdx.x * 256 + threadIdx.x;  // < 49152
    int ci3 = idx >> 7, co = idx & 127;
    w2T[ci3 * 128 + co] = w2[co * 384 + ci3];
}

// ---------------------------------------------------------------------------
// P1: xT[n][c][w][h] = x[n][c][h][w]  (bf16, unpadded 56x56 planes)
// ---------------------------------------------------------------------------
__global__ __launch_bounds__(256) void p1_transpose(const float* __restrict__ x,
                                                    __bf16* __restrict__ xT) {
    int c = blockIdx.x, n = blockIdx.y;
    __shared__ float xs[56 * 57];
    int tid = threadIdx.x;
    const float* xp = x + (size_t)(n * C_ + c) * HW_;
    for (int i = tid; i < HW_; i += 256) {
        int h = i / 56, w = i - 56 * h;
        xs[w * 57 + h] = xp[i];
    }
    __syncthreads();
    __bf16* op = xT + (size_t)(n * C_ + c) * HW_;
    for (int i = tid; i < 1568; i += 256) {
        int j = 2 * i;
        int wp = j / 56, h = j - 56 * wp;
        bf16x2 pr = {(__bf16)xs[wp * 57 + h], (__bf16)xs[wp * 57 + h + 1]};
        *(bf16x2*)&op[j] = pr;
    }
}

// ---------------------------------------------------------------------------
// K1: dense 1x3 conv, fp32. 2 h-rows/block, 2 co/thread (halves LDS traffic).
// Writes bf16 h-padded t2pb[n][co][h+3][w]. Grid (28, N_).
// ---------------------------------------------------------------------------
__global__ __launch_bounds__(256) void k1_conv1x3(const float* __restrict__ x,
                                                  const float* __restrict__ w2T,
                                                  __bf16* __restrict__ t2pb) {
    int hb = blockIdx.x, n = blockIdx.y;
    int h0 = hb * 2;
    __shared__ float xs[2 * 128 * 58];  // 59392 B
    int tid = threadIdx.x;
    const float* xbase = x + (size_t)(n * C_) * HW_;
    for (int i = tid; i < 2 * C_ * W_; i += 256) {  // 14336
        int hr = i / 7168;
        int rem = i - hr * 7168;
        int ci = rem / 56, w = rem - 56 * ci;
        xs[hr * 7424 + ci * 58 + w + 1] = xbase[ci * HW_ + (h0 + hr) * 56 + w];
    }
    {   // zero pads: one (hr,ci) per thread
        int hr = tid >> 7, ci = tid & 127;
        xs[hr * 7424 + ci * 58] = 0.f;
        xs[hr * 7424 + ci * 58 + 57] = 0.f;
    }
    __syncthreads();

    int hr = tid >> 7;
    int strip = (tid >> 6) & 1;
    int co = (tid & 63) * 2;
    int wb = strip * 28;
    float acc0[28], acc1[28];
#pragma unroll
    for (int w = 0; w < 28; w++) { acc0[w] = 0.f; acc1[w] = 0.f; }

    const float* xrow = &xs[hr * 7424];
    for (int ci = 0; ci < C_; ci++) {
        float xv[30];
        int base = ci * 58 + wb;
#pragma unroll
        for (int t = 0; t < 30; t++) xv[t] = xrow[base + t];
        float2 wa = *(const float2*)&w2T[(ci * 3 + 0) * 128 + co];
        float2 wb2 = *(const float2*)&w2T[(ci * 3 + 1) * 128 + co];
        float2 wc = *(const float2*)&w2T[(ci * 3 + 2) * 128 + co];
#pragma unroll
        for (int w = 0; w < 28; w++) {
            acc0[w] += xv[w] * wa.x + xv[w + 1] * wb2.x + xv[w + 2] * wc.x;
            acc1[w] += xv[w] * wa.y + xv[w + 1] * wb2.y + xv[w + 2] * wc.y;
        }
    }

    int h = h0 + hr;
    __bf16* o0 = t2pb + ((size_t)(n * C_ + co) * 62 + (h + 3)) * 56 + wb;
    __bf16* o1 = o0 + T2_PLANE;
#pragma unroll
    for (int w = 0; w < 28; w += 2) {
        bf16x2 p0 = {(__bf16)acc0[w], (__bf16)acc0[w + 1]};
        bf16x2 p1 = {(__bf16)acc1[w], (__bf16)acc1[w + 1]};
        *(bf16x2*)&o0[w] = p0;
        *(bf16x2*)&o1[w] = p1;
    }
}

// ---------------------------------------------------------------------------
// K2: t3[n,k,a,b] += (1/56) sum_{w,h} xT[a][w+2k-6][h] * xT[b][w][h]
// MFMA 16x16x32 bf16. Grid (8, 7, N_): 8-way split over 56 w-cols.
// ---------------------------------------------------------------------------
__global__ __launch_bounds__(256) void k2_mfma(const __bf16* __restrict__ xT,
                                               float* __restrict__ t3) {
    int hc = blockIdx.x, k = blockIdx.y, n = blockIdx.z;
    __shared__ __align__(16) __bf16 As[128 * 72];
    __shared__ __align__(16) __bf16 Bs[128 * 72];
    int tid = threadIdx.x;
    int wv = tid >> 6, lane = tid & 63;
    int lm = lane & 15, lq = lane >> 4;
    int wi = wv >> 1, wj = wv & 1;

    f32x4 acc[4][4];
    f32x4 zero4 = {0.f, 0.f, 0.f, 0.f};
#pragma unroll
    for (int i = 0; i < 4; i++)
#pragma unroll
        for (int j = 0; j < 4; j++) acc[i][j] = zero4;

    const __bf16* xTn = xT + (size_t)n * XT_PER_N;
    __bf16 bz = (__bf16)0.f;
    bf16x8 vzero = {bz, bz, bz, bz, bz, bz, bz, bz};

    for (int ci = 0; ci < 7; ci++) {
        int w = hc * 7 + ci;
        int wpA = w + 2 * k - 6;
        bool aval = (wpA >= 0 && wpA < 56);
#pragma unroll
        for (int u = 0; u < 4; u++) {
            int v = tid + u * 256;
            int m = v & 7, a = v >> 3;
            bf16x8 va = vzero, vb = vzero;
            if (m < 7) {
                if (aval) va = *(const bf16x8*)(xTn + (a * 56 + wpA) * 56 + 8 * m);
                vb = *(const bf16x8*)(xTn + (a * 56 + w) * 56 + 8 * m);
            }
            *(bf16x8*)&As[a * 72 + 8 * m] = va;
            *(bf16x8*)&Bs[a * 72 + 8 * m] = vb;
        }
        __syncthreads();
#pragma unroll
        for (int kb = 0; kb < 2; kb++) {
            bf16x8 av[4], bv[4];
#pragma unroll
            for (int i = 0; i < 4; i++)
                av[i] = *(const bf16x8*)&As[(wi * 64 + i * 16 + lm) * 72 + kb * 32 + lq * 8];
#pragma unroll
            for (int j = 0; j < 4; j++)
                bv[j] = *(const bf16x8*)&Bs[(wj * 64 + j * 16 + lm) * 72 + kb * 32 + lq * 8];
#pragma unroll
            for (int i = 0; i < 4; i++)
#pragma unroll
                for (int j = 0; j < 4; j++)
                    acc[i][j] = __builtin_amdgcn_mfma_f32_16x16x32_bf16(av[i], bv[j], acc[i][j], 0, 0, 0);
        }
        __syncthreads();
    }

    float* t3p = t3 + (size_t)(n * 7 + k) * (C_ * C_);
    const float inv56 = 1.0f / 56.0f;
#pragma unroll
    for (int i = 0; i < 4; i++)
#pragma unroll
        for (int j = 0; j < 4; j++)
#pragma unroll
            for (int r = 0; r < 4; r++) {
                int a = wi * 64 + i * 16 + lq * 4 + r;
                int b = wj * 64 + j * 16 + lm;
                atomicAdd(&t3p[a * C_ + b], acc[i][j][r] * inv56);
            }
}

// ---------------------------------------------------------------------------
// s-prep: s[n][b][ak] = bf16( t3[n][k][a][b] * p6w[a][k] * p9w[k][b] / sqrt(896) )
// ---------------------------------------------------------------------------
__global__ __launch_bounds__(256) void sprep(const float* __restrict__ t3,
                                             const float* __restrict__ p6w,
                                             const float* __restrict__ p9w,
                                             __bf16* __restrict__ s) {
    int idx = blockIdx.x * 256 + threadIdx.x;  // < 16*128*896
    int n = idx / S_PER_N;
    int rem = idx - n * S_PER_N;
    int b = rem / 896;
    int ak = rem - b * 896;
    int a = ak / 7, k = ak - 7 * a;
    const float rs = 0.03340766f;  // 1/sqrt(896)
    float v = t3[((size_t)(n * 7 + k) * C_ + a) * C_ + b] * p6w[a * 7 + k] *
              p9w[k * C_ + b] * rs;
    s[idx] = (__bf16)v;
}

// ---------------------------------------------------------------------------
// K3: pure GEMM.  t10[n][b][hw] = sum_ak s[b][ak] * t2pb_lin[a*3472 + hw + 56k]
// Tile 128(b) x 64(hw), grid (49, N_) = 784 blocks. bf16 output via LDS
// transpose -> coalesced 16B stores.
// ---------------------------------------------------------------------------
__global__ __launch_bounds__(256) void k3_mfma(const __bf16* __restrict__ s,
                                               const __bf16* __restrict__ t2pb,
                                               __bf16* __restrict__ t10) {
    int tile = blockIdx.x;  // 0..48
    int n = blockIdx.y;
    int hw0 = tile * 64;
    __shared__ __align__(16) __bf16 As[128 * 72];  // 18432 B (reused as fp32 buf)
    __shared__ __align__(16) __bf16 Bs[64 * 72];   // 9216 B
    int tid = threadIdx.x;
    int wv = tid >> 6, lane = tid & 63;
    int lm = lane & 15, lq = lane >> 4;
    int wi = wv >> 1, wj = wv & 1;

    f32x4 acc[4][2];
    f32x4 zero4 = {0.f, 0.f, 0.f, 0.f};
#pragma unroll
    for (int i = 0; i < 4; i++)
#pragma unroll
        for (int j = 0; j < 2; j++) acc[i][j] = zero4;

    const __bf16* s_n = s + (size_t)n * S_PER_N;
    const __bf16* t2n = t2pb + (size_t)n * T2_PER_N;

    for (int kb = 0; kb < 14; kb++) {
        // stage A: As[b][akl] = s_n[b*896 + kb*64 + akl]
#pragma unroll
        for (int u = 0; u < 4; u++) {
            int v = tid + u * 256;
            int m = v & 7, b = v >> 3;
            *(bf16x8*)&As[b * 72 + 8 * m] =
                *(const bf16x8*)(s_n + b * 896 + kb * 64 + 8 * m);
        }
        // stage B: Bs[row=hw_local][ak swizzled], 64 rows x 64 ak
        {
            int o = tid & 7;   // hw octet (8 rows of 8)
            int p = tid >> 3;  // ak pair, [0,32)
            int ak0 = kb * 64 + 2 * p;
            int a0 = ak0 / 7, k0 = ak0 - 7 * a0;
            int ak1 = ak0 + 1;
            int a1 = ak1 / 7, k1 = ak1 - 7 * a1;
            int hwg = hw0 + 8 * o;
            bf16x8 v0 = *(const bf16x8*)(t2n + a0 * T2_PLANE + hwg + 56 * k0);
            bf16x8 v1 = *(const bf16x8*)(t2n + a1 * T2_PLANE + hwg + 56 * k1);
            int g = p >> 2;         // ak group of 8
            int off = (2 * p) & 7;  // even offset in group
            int phys = ((g ^ o) << 3) + off;
#pragma unroll
            for (int j = 0; j < 8; j++) {
                int row = 8 * o + j;
                bf16x2 pr = {v0[j], v1[j]};
                *(bf16x2*)&Bs[row * 72 + phys] = pr;
            }
        }
        __syncthreads();
#pragma unroll
        for (int kbi = 0; kbi < 2; kbi++) {
            bf16x8 av[4], bv[2];
#pragma unroll
            for (int i = 0; i < 4; i++)
                av[i] = *(const bf16x8*)&As[(wi * 64 + i * 16 + lm) * 72 + kbi * 32 + lq * 8];
#pragma unroll
            for (int j = 0; j < 2; j++) {
                int row = wj * 32 + j * 16 + lm;
                int g = kbi * 4 + lq;
                int pg = g ^ (row >> 3);
                bv[j] = *(const bf16x8*)&Bs[row * 72 + pg * 8];
            }
#pragma unroll
            for (int i = 0; i < 4; i++)
#pragma unroll
                for (int j = 0; j < 2; j++)
                    acc[i][j] = __builtin_amdgcn_mfma_f32_16x16x32_bf16(av[i], bv[j], acc[i][j], 0, 0, 0);
        }
        __syncthreads();
    }

    // store via LDS transpose: 4 chunks of 32 b-rows x 64 hw
    float* buf = (float*)As;
    __bf16* t10n = t10 + (size_t)n * T10_PER_N;
#pragma unroll 1
    for (int i = 0; i < 4; i++) {
        __syncthreads();
#pragma unroll
        for (int j = 0; j < 2; j++)
#pragma unroll
            for (int r = 0; r < 4; r++)
                buf[(wi * 16 + lq * 4 + r) * 65 + wj * 32 + j * 16 + lm] = acc[i][j][r];
        __syncthreads();
        int row = tid >> 3, seg = tid & 7;
        int b = (row < 16) ? (i * 16 + row) : (64 + i * 16 + (row - 16));
        const float* src = &buf[row * 65 + seg * 8];
        bf16x8 o8;
#pragma unroll
        for (int d = 0; d < 8; d++) o8[d] = (__bf16)src[d];
        *(bf16x8*)(t10n + (size_t)b * HW_ + hw0 + seg * 8) = o8;
    }
}

// ---------------------------------------------------------------------------
// D: out = t8 - t10 + t7, one block per (n,b) plane. LDS-staged x (padded,
// branch-free 25-tap) and t2 (fp32). 14-wide strips per thread.
// ---------------------------------------------------------------------------
__global__ __launch_bounds__(256) void d_final(const float* __restrict__ x,
                                               const __bf16* __restrict__ t2pb,
                                               const __bf16* __restrict__ t10,
                                               const float* __restrict__ w7,
                                               const float* __restrict__ w8,
                                               float* __restrict__ out) {
    int b = blockIdx.x, n = blockIdx.y;
    __shared__ float xs[64 * 65];   // [hh][ww], x[hh-4][ww-4], zero-padded
    __shared__ float t2s[56 * 60];  // [h][w+2], zero-padded cols
    int tid = threadIdx.x;
    const float* xp = x + (size_t)(n * C_ + b) * HW_;
    for (int i = tid; i < 64 * 65; i += 256) {
        int hh = i / 65, ww = i - 65 * hh;
        int h = hh - 4, w = ww - 4;
        float v = (h >= 0 && h < 56 && w >= 0 && w < 56) ? xp[h * 56 + w] : 0.f;
        xs[i] = v;
    }
    const __bf16* t2p = t2pb + (size_t)(n * C_ + b) * T2_PLANE;
    for (int i = tid; i < 56 * 60; i += 256) {
        int h = i / 60, ww = i - 60 * h;
        int w = ww - 2;
        float v = (w >= 0 && w < 56) ? (float)t2p[(h + 3) * 56 + w] : 0.f;
        t2s[i] = v;
    }
    __syncthreads();

    int r = tid >> 2;  // row
    if (r >= 56) return;
    int w0 = (tid & 3) * 14;

    float w7r[5], w8r[25];
#pragma unroll
    for (int q = 0; q < 5; q++) w7r[q] = w7[b * 5 + q];
#pragma unroll
    for (int q = 0; q < 25; q++) w8r[q] = w8[b * 25 + q];

    float acc[14];
    {   // t7
        float tw[18];
#pragma unroll
        for (int c = 0; c < 18; c++) tw[c] = t2s[r * 60 + w0 + c];
#pragma unroll
        for (int i = 0; i < 14; i++)
            acc[i] = tw[i] * w7r[0] + tw[i + 1] * w7r[1] + tw[i + 2] * w7r[2] +
                     tw[i + 3] * w7r[3] + tw[i + 4] * w7r[4];
    }
#pragma unroll
    for (int p = 0; p < 5; p++) {  // t8
        float xv[22];
        int base = (r + 2 * p) * 65 + w0;
#pragma unroll
        for (int c = 0; c < 22; c++) xv[c] = xs[base + c];
#pragma unroll
        for (int i = 0; i < 14; i++)
            acc[i] += xv[i] * w8r[p * 5 + 0] + xv[i + 2] * w8r[p * 5 + 1] +
                      xv[i + 4] * w8r[p * 5 + 2] + xv[i + 6] * w8r[p * 5 + 3] +
                      xv[i + 8] * w8r[p * 5 + 4];
    }
    const __bf16* t10r = t10 + (size_t)(n * C_ + b) * HW_ + r * 56 + w0;
    float* outr = out + (size_t)(n * C_ + b) * HW_ + r * 56 + w0;
#pragma unroll
    for (int i = 0; i < 14; i++) outr[i] = acc[i] - (float)t10r[i];
}

extern "C" void kernel_launch(void* const* d_in, const int* in_sizes, int n_in,
                              void* d_out, int out_size, void* d_ws, size_t ws_size,
                              hipStream_t stream) {
    const float* x = (const float*)d_in[0];
    const float* w2 = (const float*)d_in[1];
    const float* p6w = (const float*)d_in[2];
    const float* w7 = (const float*)d_in[3];
    const float* w8 = (const float*)d_in[4];
    const float* p9w = (const float*)d_in[5];
    float* outp = (float*)d_out;

    char* ws = (char*)d_ws;
    __bf16* xT = (__bf16*)ws;                       // [0, 12845056)
    __bf16* s = (__bf16*)ws;                        // overlay (xT dead after k2)
    __bf16* t10 = (__bf16*)(ws + WS_T10_OFF);       // [3670016, 16515072) (t3 dead)
    float* t3 = (float*)(ws + WS_T3_OFF);           // [12845056, 20185088)
    __bf16* t2pb = (__bf16*)(ws + WS_T2PB_OFF);     // [20185088, 34406400)
    float* w2T = (float*)(ws + WS_W2T_OFF);         // [34406400, 34603008)

    hipMemsetAsync(t2pb, 0, (size_t)N_ * C_ * T2_PLANE * sizeof(__bf16), stream);
    hipMemsetAsync(t3, 0, (size_t)N_ * 7 * C_ * C_ * sizeof(float), stream);

    w2t_prep<<<dim3(192), 256, 0, stream>>>(w2, w2T);
    p1_transpose<<<dim3(C_, N_), 256, 0, stream>>>(x, xT);
    k1_conv1x3<<<dim3(28, N_), 256, 0, stream>>>(x, w2T, t2pb);
    k2_mfma<<<dim3(8, 7, N_), 256, 0, stream>>>(xT, t3);
    sprep<<<dim3((N_ * S_PER_N) / 256), 256, 0, stream>>>(t3, p6w, p9w, s);
    k3_mfma<<<dim3(49, N_), 256, 0, stream>>>(s, t2pb, t10);
    d_final<<<dim3(C_, N_), 256, 0, stream>>>(x, t2pb, t10, w7, w8, outp);
}

// Round 4
// 233.015 us; speedup vs baseline: 5.3386x; 1.3446x over previous
//
#include <hip/hip_runtime.h>

#define N_ 16
#define C_ 128
#define H_ 56
#define W_ 56
#define HW_ 3136

typedef __bf16 bf16x8 __attribute__((ext_vector_type(8)));
typedef __bf16 bf16x2 __attribute__((ext_vector_type(2)));
typedef float f32x4 __attribute__((ext_vector_type(4)));

#define XT_PER_N 401408   // 128*3136 (unpadded transposed x, bf16)
#define T2_PLANE 3472     // 62*56 per channel (h-padded t2, bf16)
#define T2_PER_N 444416   // 128*3472
#define S_PER_N 114688    // 128*896
#define T10_PER_N 401408  // 128*3136

// workspace byte offsets (same proven layout as r3; w2b bf16 at old w2T slot)
#define WS_T10_OFF   3670016u
#define WS_T3_OFF    12845056u
#define WS_T2PB_OFF  20185088u
#define WS_W2B_OFF   34406400u  // 98304 B, end 34504704

// ---------------------------------------------------------------------------
// w2b[co][j*128+ci] = bf16(w2[co][ci*3+j])  — A-operand pack for k1 MFMA
// ---------------------------------------------------------------------------
__global__ __launch_bounds__(256) void w2b_prep(const float* __restrict__ w2,
                                                __bf16* __restrict__ w2b) {
    int idx = blockIdx.x * 256 + threadIdx.x;  // < 49152
    int co = idx / 384, kk = idx - co * 384;
    int j = kk >> 7, ci = kk & 127;
    w2b[idx] = (__bf16)w2[co * 384 + ci * 3 + j];
}

// ---------------------------------------------------------------------------
// P1: xT[n][c][w][h] = x[n][c][h][w]  (bf16, unpadded 56x56 planes)
// ---------------------------------------------------------------------------
__global__ __launch_bounds__(256) void p1_transpose(const float* __restrict__ x,
                                                    __bf16* __restrict__ xT) {
    int c = blockIdx.x, n = blockIdx.y;
    __shared__ float xs[56 * 57];
    int tid = threadIdx.x;
    const float* xp = x + (size_t)(n * C_ + c) * HW_;
    for (int i = tid; i < HW_; i += 256) {
        int h = i / 56, w = i - 56 * h;
        xs[w * 57 + h] = xp[i];
    }
    __syncthreads();
    __bf16* op = xT + (size_t)(n * C_ + c) * HW_;
    for (int i = tid; i < 1568; i += 256) {
        int j = 2 * i;
        int wp = j / 56, h = j - 56 * wp;
        bf16x2 pr = {(__bf16)xs[wp * 57 + h], (__bf16)xs[wp * 57 + h + 1]};
        *(bf16x2*)&op[j] = pr;
    }
}

// ---------------------------------------------------------------------------
// K1 (MFMA): t2[co][w] = sum_{kk=(j,ci)} w2b[co][kk] * x[ci][h][w+j-1]
// Per (h,n) block: M=128 co, N=64 w (56 valid), K=384 in 6 chunks of 64.
// Bs[wp][ci] staged UNSHIFTED (row wp <-> x w-index wp-1); the j-shift is
// applied at fragment-read time via the LDS row index (w_local + j).
// Output via LDS transpose -> coalesced bf16x8 stores into h-padded t2pb.
// ---------------------------------------------------------------------------
__global__ __launch_bounds__(256) void k1_mfma(const float* __restrict__ x,
                                               const __bf16* __restrict__ w2b,
                                               __bf16* __restrict__ t2pb) {
    int h = blockIdx.x, n = blockIdx.y;
    __shared__ __align__(16) __bf16 Bs[66 * 136];  // 17952 B
    __shared__ __align__(16) __bf16 As[128 * 72];  // 18432 B (reused for store)
    int tid = threadIdx.x;
    int wv = tid >> 6, lane = tid & 63;
    int lm = lane & 15, lq = lane >> 4;
    int wi = wv >> 1, wj = wv & 1;

    // stage Bs once: Bs[wp*136 + ci] = x[ci][h][wp-1] (0 outside [0,56))
    const float* xn = x + (size_t)n * C_ * HW_ + h * 56;
    for (int i = tid; i < 66 * 128; i += 256) {
        int ci = i / 66, wp = i - 66 * ci;
        int wx = wp - 1;
        float v = (wx >= 0 && wx < 56) ? xn[ci * HW_ + wx] : 0.f;
        Bs[wp * 136 + ci] = (__bf16)v;
    }

    f32x4 acc[4][2];
    f32x4 zero4 = {0.f, 0.f, 0.f, 0.f};
#pragma unroll
    for (int i = 0; i < 4; i++)
#pragma unroll
        for (int j = 0; j < 2; j++) acc[i][j] = zero4;

    const __bf16* w2n = w2b;
    for (int c6 = 0; c6 < 6; c6++) {
        // stage As[co][0..63] = w2b[co][c6*64 .. +63]
#pragma unroll
        for (int u = 0; u < 4; u++) {
            int v = tid + u * 256;
            int m = v & 7, co = v >> 3;
            *(bf16x8*)&As[co * 72 + 8 * m] =
                *(const bf16x8*)(w2n + co * 384 + c6 * 64 + 8 * m);
        }
        __syncthreads();
#pragma unroll
        for (int kl = 0; kl < 2; kl++) {
            int ks = c6 * 2 + kl;        // k-step 0..11
            int j = ks >> 2;             // tap 0..2
            int cbase = (ks & 3) * 32;   // ci block base
            bf16x8 av[4], bv[2];
#pragma unroll
            for (int i = 0; i < 4; i++)
                av[i] = *(const bf16x8*)&As[(wi * 64 + i * 16 + lm) * 72 + kl * 32 + lq * 8];
#pragma unroll
            for (int jt = 0; jt < 2; jt++) {
                int row = wj * 32 + jt * 16 + lm + j;
                bv[jt] = *(const bf16x8*)&Bs[row * 136 + cbase + lq * 8];
            }
#pragma unroll
            for (int i = 0; i < 4; i++)
#pragma unroll
                for (int jt = 0; jt < 2; jt++)
                    acc[i][jt] = __builtin_amdgcn_mfma_f32_16x16x32_bf16(av[i], bv[jt], acc[i][jt], 0, 0, 0);
        }
        __syncthreads();
    }

    // store via LDS transpose: 4 chunks of 32 co-rows x 64 w
    float* buf = (float*)As;
    __bf16* t2n = t2pb + (size_t)n * T2_PER_N;
#pragma unroll 1
    for (int i = 0; i < 4; i++) {
        __syncthreads();
#pragma unroll
        for (int jt = 0; jt < 2; jt++)
#pragma unroll
            for (int r = 0; r < 4; r++)
                buf[(wi * 16 + lq * 4 + r) * 65 + wj * 32 + jt * 16 + lm] = acc[i][jt][r];
        __syncthreads();
        int row = tid >> 3, seg = tid & 7;
        if (seg < 7) {
            int co = (row < 16) ? (i * 16 + row) : (64 + i * 16 + (row - 16));
            const float* src = &buf[row * 65 + seg * 8];
            bf16x8 o8;
#pragma unroll
            for (int d = 0; d < 8; d++) o8[d] = (__bf16)src[d];
            *(bf16x8*)(t2n + (size_t)co * T2_PLANE + (h + 3) * 56 + seg * 8) = o8;
        }
    }
}

// ---------------------------------------------------------------------------
// K2: t3[n,k,a,b] += (1/56) sum_{w,h} xT[a][w+2k-6][h] * xT[b][w][h]
// MFMA 16x16x32 bf16. Grid (4, 7, N_): 4-way split over 56 w-cols.
// ---------------------------------------------------------------------------
__global__ __launch_bounds__(256) void k2_mfma(const __bf16* __restrict__ xT,
                                               float* __restrict__ t3) {
    int hc = blockIdx.x, k = blockIdx.y, n = blockIdx.z;
    __shared__ __align__(16) __bf16 As[128 * 72];
    __shared__ __align__(16) __bf16 Bs[128 * 72];
    int tid = threadIdx.x;
    int wv = tid >> 6, lane = tid & 63;
    int lm = lane & 15, lq = lane >> 4;
    int wi = wv >> 1, wj = wv & 1;

    f32x4 acc[4][4];
    f32x4 zero4 = {0.f, 0.f, 0.f, 0.f};
#pragma unroll
    for (int i = 0; i < 4; i++)
#pragma unroll
        for (int j = 0; j < 4; j++) acc[i][j] = zero4;

    const __bf16* xTn = xT + (size_t)n * XT_PER_N;
    __bf16 bz = (__bf16)0.f;
    bf16x8 vzero = {bz, bz, bz, bz, bz, bz, bz, bz};

    for (int ci = 0; ci < 14; ci++) {
        int w = hc * 14 + ci;
        int wpA = w + 2 * k - 6;
        bool aval = (wpA >= 0 && wpA < 56);
#pragma unroll
        for (int u = 0; u < 4; u++) {
            int v = tid + u * 256;
            int m = v & 7, a = v >> 3;
            bf16x8 va = vzero, vb = vzero;
            if (m < 7) {
                if (aval) va = *(const bf16x8*)(xTn + (a * 56 + wpA) * 56 + 8 * m);
                vb = *(const bf16x8*)(xTn + (a * 56 + w) * 56 + 8 * m);
            }
            *(bf16x8*)&As[a * 72 + 8 * m] = va;
            *(bf16x8*)&Bs[a * 72 + 8 * m] = vb;
        }
        __syncthreads();
#pragma unroll
        for (int kb = 0; kb < 2; kb++) {
            bf16x8 av[4], bv[4];
#pragma unroll
            for (int i = 0; i < 4; i++)
                av[i] = *(const bf16x8*)&As[(wi * 64 + i * 16 + lm) * 72 + kb * 32 + lq * 8];
#pragma unroll
            for (int j = 0; j < 4; j++)
                bv[j] = *(const bf16x8*)&Bs[(wj * 64 + j * 16 + lm) * 72 + kb * 32 + lq * 8];
#pragma unroll
            for (int i = 0; i < 4; i++)
#pragma unroll
                for (int j = 0; j < 4; j++)
                    acc[i][j] = __builtin_amdgcn_mfma_f32_16x16x32_bf16(av[i], bv[j], acc[i][j], 0, 0, 0);
        }
        __syncthreads();
    }

    float* t3p = t3 + (size_t)(n * 7 + k) * (C_ * C_);
    const float inv56 = 1.0f / 56.0f;
#pragma unroll
    for (int i = 0; i < 4; i++)
#pragma unroll
        for (int j = 0; j < 4; j++)
#pragma unroll
            for (int r = 0; r < 4; r++) {
                int a = wi * 64 + i * 16 + lq * 4 + r;
                int b = wj * 64 + j * 16 + lm;
                atomicAdd(&t3p[a * C_ + b], acc[i][j][r] * inv56);
            }
}

// ---------------------------------------------------------------------------
// s-prep: s[n][b][ak] = bf16( t3[n][k][a][b] * p6w[a][k] * p9w[k][b] / sqrt(896) )
// ---------------------------------------------------------------------------
__global__ __launch_bounds__(256) void sprep(const float* __restrict__ t3,
                                             const float* __restrict__ p6w,
                                             const float* __restrict__ p9w,
                                             __bf16* __restrict__ s) {
    int idx = blockIdx.x * 256 + threadIdx.x;  // < 16*128*896
    int n = idx / S_PER_N;
    int rem = idx - n * S_PER_N;
    int b = rem / 896;
    int ak = rem - b * 896;
    int a = ak / 7, k = ak - 7 * a;
    const float rs = 0.03340766f;  // 1/sqrt(896)
    float v = t3[((size_t)(n * 7 + k) * C_ + a) * C_ + b] * p6w[a * 7 + k] *
              p9w[k * C_ + b] * rs;
    s[idx] = (__bf16)v;
}

// ---------------------------------------------------------------------------
// K3: pure GEMM.  t10[n][b][hw] = sum_ak s[b][ak] * t2pb_lin[a*3472 + hw + 56k]
// Tile 128(b) x 64(hw), grid (49, N_). bf16 output via LDS transpose.
// ---------------------------------------------------------------------------
__global__ __launch_bounds__(256) void k3_mfma(const __bf16* __restrict__ s,
                                               const __bf16* __restrict__ t2pb,
                                               __bf16* __restrict__ t10) {
    int tile = blockIdx.x;  // 0..48
    int n = blockIdx.y;
    int hw0 = tile * 64;
    __shared__ __align__(16) __bf16 As[128 * 72];
    __shared__ __align__(16) __bf16 Bs[64 * 72];
    int tid = threadIdx.x;
    int wv = tid >> 6, lane = tid & 63;
    int lm = lane & 15, lq = lane >> 4;
    int wi = wv >> 1, wj = wv & 1;

    f32x4 acc[4][2];
    f32x4 zero4 = {0.f, 0.f, 0.f, 0.f};
#pragma unroll
    for (int i = 0; i < 4; i++)
#pragma unroll
        for (int j = 0; j < 2; j++) acc[i][j] = zero4;

    const __bf16* s_n = s + (size_t)n * S_PER_N;
    const __bf16* t2n = t2pb + (size_t)n * T2_PER_N;

    for (int kb = 0; kb < 14; kb++) {
#pragma unroll
        for (int u = 0; u < 4; u++) {
            int v = tid + u * 256;
            int m = v & 7, b = v >> 3;
            *(bf16x8*)&As[b * 72 + 8 * m] =
                *(const bf16x8*)(s_n + b * 896 + kb * 64 + 8 * m);
        }
        {
            int o = tid & 7;   // hw octet
            int p = tid >> 3;  // ak pair, [0,32)
            int ak0 = kb * 64 + 2 * p;
            int a0 = ak0 / 7, k0 = ak0 - 7 * a0;
            int ak1 = ak0 + 1;
            int a1 = ak1 / 7, k1 = ak1 - 7 * a1;
            int hwg = hw0 + 8 * o;
            bf16x8 v0 = *(const bf16x8*)(t2n + a0 * T2_PLANE + hwg + 56 * k0);
            bf16x8 v1 = *(const bf16x8*)(t2n + a1 * T2_PLANE + hwg + 56 * k1);
            int g = p >> 2;
            int off = (2 * p) & 7;
            int phys = ((g ^ o) << 3) + off;
#pragma unroll
            for (int j = 0; j < 8; j++) {
                int row = 8 * o + j;
                bf16x2 pr = {v0[j], v1[j]};
                *(bf16x2*)&Bs[row * 72 + phys] = pr;
            }
        }
        __syncthreads();
#pragma unroll
        for (int kbi = 0; kbi < 2; kbi++) {
            bf16x8 av[4], bv[2];
#pragma unroll
            for (int i = 0; i < 4; i++)
                av[i] = *(const bf16x8*)&As[(wi * 64 + i * 16 + lm) * 72 + kbi * 32 + lq * 8];
#pragma unroll
            for (int j = 0; j < 2; j++) {
                int row = wj * 32 + j * 16 + lm;
                int g = kbi * 4 + lq;
                int pg = g ^ (row >> 3);
                bv[j] = *(const bf16x8*)&Bs[row * 72 + pg * 8];
            }
#pragma unroll
            for (int i = 0; i < 4; i++)
#pragma unroll
                for (int j = 0; j < 2; j++)
                    acc[i][j] = __builtin_amdgcn_mfma_f32_16x16x32_bf16(av[i], bv[j], acc[i][j], 0, 0, 0);
        }
        __syncthreads();
    }

    float* buf = (float*)As;
    __bf16* t10n = t10 + (size_t)n * T10_PER_N;
#pragma unroll 1
    for (int i = 0; i < 4; i++) {
        __syncthreads();
#pragma unroll
        for (int j = 0; j < 2; j++)
#pragma unroll
            for (int r = 0; r < 4; r++)
                buf[(wi * 16 + lq * 4 + r) * 65 + wj * 32 + j * 16 + lm] = acc[i][j][r];
        __syncthreads();
        int row = tid >> 3, seg = tid & 7;
        int b = (row < 16) ? (i * 16 + row) : (64 + i * 16 + (row - 16));
        const float* src = &buf[row * 65 + seg * 8];
        bf16x8 o8;
#pragma unroll
        for (int d = 0; d < 8; d++) o8[d] = (__bf16)src[d];
        *(bf16x8*)(t10n + (size_t)b * HW_ + hw0 + seg * 8) = o8;
    }
}

// ---------------------------------------------------------------------------
// D: out = t8 - t10 + t7, one block per (n,b) plane.
// ---------------------------------------------------------------------------
__global__ __launch_bounds__(256) void d_final(const float* __restrict__ x,
                                               const __bf16* __restrict__ t2pb,
                                               const __bf16* __restrict__ t10,
                                               const float* __restrict__ w7,
                                               const float* __restrict__ w8,
                                               float* __restrict__ out) {
    int b = blockIdx.x, n = blockIdx.y;
    __shared__ float xs[64 * 65];
    __shared__ float t2s[56 * 60];
    int tid = threadIdx.x;
    const float* xp = x + (size_t)(n * C_ + b) * HW_;
    for (int i = tid; i < 64 * 65; i += 256) {
        int hh = i / 65, ww = i - 65 * hh;
        int h = hh - 4, w = ww - 4;
        float v = (h >= 0 && h < 56 && w >= 0 && w < 56) ? xp[h * 56 + w] : 0.f;
        xs[i] = v;
    }
    const __bf16* t2p = t2pb + (size_t)(n * C_ + b) * T2_PLANE;
    for (int i = tid; i < 56 * 60; i += 256) {
        int h = i / 60, ww = i - 60 * h;
        int w = ww - 2;
        float v = (w >= 0 && w < 56) ? (float)t2p[(h + 3) * 56 + w] : 0.f;
        t2s[i] = v;
    }
    __syncthreads();

    int r = tid >> 2;
    if (r >= 56) return;
    int w0 = (tid & 3) * 14;

    float w7r[5], w8r[25];
#pragma unroll
    for (int q = 0; q < 5; q++) w7r[q] = w7[b * 5 + q];
#pragma unroll
    for (int q = 0; q < 25; q++) w8r[q] = w8[b * 25 + q];

    float acc[14];
    {
        float tw[18];
#pragma unroll
        for (int c = 0; c < 18; c++) tw[c] = t2s[r * 60 + w0 + c];
#pragma unroll
        for (int i = 0; i < 14; i++)
            acc[i] = tw[i] * w7r[0] + tw[i + 1] * w7r[1] + tw[i + 2] * w7r[2] +
                     tw[i + 3] * w7r[3] + tw[i + 4] * w7r[4];
    }
#pragma unroll
    for (int p = 0; p < 5; p++) {
        float xv[22];
        int base = (r + 2 * p) * 65 + w0;
#pragma unroll
        for (int c = 0; c < 22; c++) xv[c] = xs[base + c];
#pragma unroll
        for (int i = 0; i < 14; i++)
            acc[i] += xv[i] * w8r[p * 5 + 0] + xv[i + 2] * w8r[p * 5 + 1] +
                      xv[i + 4] * w8r[p * 5 + 2] + xv[i + 6] * w8r[p * 5 + 3] +
                      xv[i + 8] * w8r[p * 5 + 4];
    }
    const __bf16* t10r = t10 + (size_t)(n * C_ + b) * HW_ + r * 56 + w0;
    float* outr = out + (size_t)(n * C_ + b) * HW_ + r * 56 + w0;
#pragma unroll
    for (int i = 0; i < 14; i++) outr[i] = acc[i] - (float)t10r[i];
}

extern "C" void kernel_launch(void* const* d_in, const int* in_sizes, int n_in,
                              void* d_out, int out_size, void* d_ws, size_t ws_size,
                              hipStream_t stream) {
    const float* x = (const float*)d_in[0];
    const float* w2 = (const float*)d_in[1];
    const float* p6w = (const float*)d_in[2];
    const float* w7 = (const float*)d_in[3];
    const float* w8 = (const float*)d_in[4];
    const float* p9w = (const float*)d_in[5];
    float* outp = (float*)d_out;

    char* ws = (char*)d_ws;
    __bf16* xT = (__bf16*)ws;
    __bf16* s = (__bf16*)ws;                     // overlay (xT dead after k2)
    __bf16* t10 = (__bf16*)(ws + WS_T10_OFF);    // overlays xT tail + t3 head
    float* t3 = (float*)(ws + WS_T3_OFF);
    __bf16* t2pb = (__bf16*)(ws + WS_T2PB_OFF);
    __bf16* w2b = (__bf16*)(ws + WS_W2B_OFF);

    hipMemsetAsync(t2pb, 0, (size_t)N_ * C_ * T2_PLANE * sizeof(__bf16), stream);
    hipMemsetAsync(t3, 0, (size_t)N_ * 7 * C_ * C_ * sizeof(float), stream);

    w2b_prep<<<dim3(192), 256, 0, stream>>>(w2, w2b);
    p1_transpose<<<dim3(C_, N_), 256, 0, stream>>>(x, xT);
    k1_mfma<<<dim3(H_, N_), 256, 0, stream>>>(x, w2b, t2pb);
    k2_mfma<<<dim3(4, 7, N_), 256, 0, stream>>>(xT, t3);
    sprep<<<dim3((N_ * S_PER_N) / 256), 256, 0, stream>>>(t3, p6w, p9w, s);
    k3_mfma<<<dim3(49, N_), 256, 0, stream>>>(s, t2pb, t10);
    d_final<<<dim3(C_, N_), 256, 0, stream>>>(x, t2pb, t10, w7, w8, outp);
}